// Round 8
// baseline (374.964 us; speedup 1.0000x reference)
//
#include <hip/hip_runtime.h>

// GraphSAGE forward: lin+relu -> SAGEConv(mean)+relu -> SAGEConv(mean) -> log_softmax
// N=100000, E=1.6M, dims 128 -> 128 -> 128 -> 64.
//
// Round 8: conv1 gather XCD-panelized. h1 stored as 8 column-panels [8][N][16]
// (3.2MB each, fits one XCD's 4MB L2); gather blocks pinned panel=blockIdx%8
// (empirical RR blockIdx->XCD). Random gather becomes L2-resident per XCD.
// gemm_lin writes panel layout; gemm_c1 stages B from panels. Rest: round 7.

#define KDIM 128
#define CH 16384            // edges per multisplit chunk
#define BSH 8               // bucket = dst >> 8 (256 nodes/bucket)
#define BCAP 8192           // per-bucket LDS capacity (avg ~4100)

using bf16x8 = __attribute__((ext_vector_type(8))) short;
using f32x4  = __attribute__((ext_vector_type(4))) float;

__device__ __forceinline__ unsigned short f2bf_u(float f) {
    unsigned u = __float_as_uint(f);
    u += 0x7fffu + ((u >> 16) & 1u);
    return (unsigned short)(u >> 16);
}
__device__ __forceinline__ unsigned packbf2(float a, float b) {
    return (unsigned)f2bf_u(a) | ((unsigned)f2bf_u(b) << 16);
}
__device__ __forceinline__ float bf2f(short s) {
    return __uint_as_float(((unsigned)(unsigned short)s) << 16);
}
__device__ __forceinline__ float ulo(unsigned u) { return __uint_as_float(u << 16); }
__device__ __forceinline__ float uhi(unsigned u) { return __uint_as_float(u & 0xffff0000u); }

__device__ __forceinline__ void gload_lds16(const short* g, short* l) {
    __builtin_amdgcn_global_load_lds(
        (const __attribute__((address_space(1))) unsigned int*)g,
        (__attribute__((address_space(3))) unsigned int*)l, 16, 0, 0);
}

// ---- multisplit CSR build ----

__global__ __launch_bounds__(256) void bin_hist(
    const int* __restrict__ ei, int* __restrict__ hist, int E, int nwg, int NB)
{
    __shared__ int lh[512];
    const int w = blockIdx.x, t = threadIdx.x;
    for (int b = t; b < NB; b += 256) lh[b] = 0;
    __syncthreads();
    const int e0 = w * CH, e1 = min(E, e0 + CH);
    for (int e = e0 + t; e < e1; e += 256)
        atomicAdd(&lh[ei[E + e] >> BSH], 1);
    __syncthreads();
    for (int b = t; b < NB; b += 256) hist[b * nwg + w] = lh[b];
}

__global__ __launch_bounds__(256) void greduce(
    const int* __restrict__ in, int* __restrict__ bsum, int n)
{
    const int t = threadIdx.x;
    const int idx = blockIdx.x * 1024 + t * 4;
    int s = 0;
    if (idx + 4 <= n) {
        int4 a = *(const int4*)(in + idx);
        s = a.x + a.y + a.z + a.w;
    } else {
        #pragma unroll
        for (int k = 0; k < 4; ++k) if (idx + k < n) s += in[idx + k];
    }
    #pragma unroll
    for (int d = 1; d < 64; d <<= 1) s += __shfl_xor(s, d);
    __shared__ int ws[4];
    if ((t & 63) == 0) ws[t >> 6] = s;
    __syncthreads();
    if (t == 0) bsum[blockIdx.x] = ws[0] + ws[1] + ws[2] + ws[3];
}

__global__ __launch_bounds__(256) void scan_bsums(int* __restrict__ bsum, int nb)
{
    const int t = threadIdx.x;
    const int lane = t & 63, wid = t >> 6;
    int v = (t < nb) ? bsum[t] : 0;
    int incl = v;
    #pragma unroll
    for (int d = 1; d < 64; d <<= 1) {
        int u = __shfl_up(incl, d);
        if (lane >= d) incl += u;
    }
    __shared__ int ws[4];
    if (lane == 63) ws[wid] = incl;
    __syncthreads();
    int woff = 0;
    #pragma unroll
    for (int w = 0; w < 4; ++w) if (w < wid) woff += ws[w];
    const int excl = woff + incl - v;
    if (t <= nb) bsum[t] = excl;
}

__global__ __launch_bounds__(256) void gapply(
    int* __restrict__ io, const int* __restrict__ bsum, int n)
{
    const int t = threadIdx.x;
    const int lane = t & 63, wid = t >> 6;
    const int idx = blockIdx.x * 1024 + t * 4;
    int v[4] = {0, 0, 0, 0};
    if (idx + 4 <= n) {
        int4 a = *(const int4*)(io + idx);
        v[0] = a.x; v[1] = a.y; v[2] = a.z; v[3] = a.w;
    } else {
        #pragma unroll
        for (int k = 0; k < 4; ++k) if (idx + k < n) v[k] = io[idx + k];
    }
    const int sum = v[0] + v[1] + v[2] + v[3];
    int incl = sum;
    #pragma unroll
    for (int d = 1; d < 64; d <<= 1) {
        int u = __shfl_up(incl, d);
        if (lane >= d) incl += u;
    }
    __shared__ int ws[4];
    if (lane == 63) ws[wid] = incl;
    __syncthreads();
    int woff = 0;
    #pragma unroll
    for (int w = 0; w < 4; ++w) if (w < wid) woff += ws[w];
    int excl = bsum[blockIdx.x] + woff + (incl - sum);
    if (idx + 4 <= n) {
        int4 o;
        o.x = excl; o.y = excl + v[0]; o.z = excl + v[0] + v[1];
        o.w = excl + v[0] + v[1] + v[2];
        *(int4*)(io + idx) = o;
    } else {
        #pragma unroll
        for (int k = 0; k < 4; ++k) {
            if (idx + k < n) { io[idx + k] = excl; excl += v[k]; }
        }
    }
}

__global__ __launch_bounds__(256) void bin_scatter(
    const int* __restrict__ ei, const int* __restrict__ hist_s,
    unsigned* __restrict__ packed, int E, int nwg, int NB)
{
    __shared__ int lc[512];
    const int w = blockIdx.x, t = threadIdx.x;
    for (int b = t; b < NB; b += 256) lc[b] = hist_s[b * nwg + w];
    __syncthreads();
    const int e0 = w * CH, e1 = min(E, e0 + CH);
    for (int e = e0 + t; e < e1; e += 256) {
        const int src = ei[e];
        const int dst = ei[E + e];
        const int b = dst >> BSH;
        const int pos = atomicAdd(&lc[b], 1);
        packed[pos] = ((unsigned)(dst & 255) << 17) | (unsigned)src;
    }
}

__global__ __launch_bounds__(256) void bucket_sort(
    const unsigned* __restrict__ packed, const int* __restrict__ hist_s,
    int* __restrict__ offs, float* __restrict__ degf, int* __restrict__ perm,
    int E, int nwg, int NB, int N)
{
    __shared__ unsigned le[BCAP];
    __shared__ int lp[BCAP];
    __shared__ int lh[256], lx[256], lc[256];
    __shared__ int ws[4];
    const int b = blockIdx.x, t = threadIdx.x;
    const int bb = hist_s[b * nwg];
    const int be = (b + 1 < NB) ? hist_s[(b + 1) * nwg] : E;
    int cnt = be - bb;
    if (cnt > BCAP) cnt = BCAP;
    for (int i = t; i < cnt; i += 256) le[i] = packed[bb + i];
    lh[t] = 0;
    __syncthreads();
    for (int i = t; i < cnt; i += 256) atomicAdd(&lh[le[i] >> 17], 1);
    __syncthreads();
    const int lane = t & 63, wid = t >> 6;
    const int v = lh[t];
    int incl = v;
    #pragma unroll
    for (int d = 1; d < 64; d <<= 1) {
        int u = __shfl_up(incl, d);
        if (lane >= d) incl += u;
    }
    if (lane == 63) ws[wid] = incl;
    __syncthreads();
    int woff = 0;
    #pragma unroll
    for (int w = 0; w < 4; ++w) if (w < wid) woff += ws[w];
    const int excl = woff + incl - v;
    lx[t] = excl;
    lc[t] = excl;
    __syncthreads();
    for (int i = t; i < cnt; i += 256) {
        const unsigned p = le[i];
        const int pos = atomicAdd(&lc[p >> 17], 1);
        lp[pos] = (int)(p & 0x1FFFFu);
    }
    __syncthreads();
    for (int i = t; i < cnt; i += 256) perm[bb + i] = lp[i];
    const int node = (b << BSH) + t;
    if (node < N) {
        offs[node] = bb + lx[t];
        degf[node] = (float)v;
    }
    if (b == NB - 1 && t == 0) offs[N] = E;
}

// ---- operand prep ----

// wp[ks][cf][lane][j] = bf16(W[cf*16 + (lane&15)][ks*32 + (lane>>4)*8 + j])
__global__ __launch_bounds__(256) void pack_weights(
    const float* __restrict__ Wlin, const float* __restrict__ Wc1l,
    const float* __restrict__ Wc1r, const float* __restrict__ Wc2l,
    const float* __restrict__ Wc2r, short* __restrict__ wp)
{
    int idx = blockIdx.x * 256 + threadIdx.x;   // 0..65535
    if (idx >= 65536) return;
    const float* W; short* dst; int off, ncf;
    if (idx < 16384)      { W = Wlin; dst = wp;         off = idx;         ncf = 8; }
    else if (idx < 32768) { W = Wc1l; dst = wp + 16384; off = idx - 16384; ncf = 8; }
    else if (idx < 49152) { W = Wc1r; dst = wp + 32768; off = idx - 32768; ncf = 8; }
    else if (idx < 57344) { W = Wc2l; dst = wp + 49152; off = idx - 49152; ncf = 4; }
    else                  { W = Wc2r; dst = wp + 57344; off = idx - 57344; ncf = 4; }
    int j    = off & 7;
    int lane = (off >> 3) & 63;
    int cf   = (off >> 9) & (ncf - 1);
    int ks   = off >> ((ncf == 8) ? 12 : 11);
    int m = cf * 16 + (lane & 15);
    int k = ks * 32 + ((lane >> 4) << 3) + j;
    dst[off] = (short)f2bf_u(W[m * KDIM + k]);
}

// ---- gathers ----

// conv1, XCD-panelized: h1p = [8][N][16] bf16 panels. panel = blockIdx%8 -> XCD
// affinity (empirical RR). One wave per (node, panel): 16 edge-groups x 4 lanes
// x 8B. agg[n][panel*16..+16] = bf16(sum/max(deg,1)).
__global__ __launch_bounds__(256) void gather_mean_panel(
    const short* __restrict__ h1p, const int* __restrict__ offs,
    const int* __restrict__ perm, const float* __restrict__ degf,
    short* __restrict__ agg, int N)
{
    const int panel = blockIdx.x & 7;
    const int node = (blockIdx.x >> 3) * 4 + (threadIdx.x >> 6);
    if (node >= N) return;
    const int l = threadIdx.x & 63;
    const int g = l >> 2;            // edge group 0..15
    const int c = l & 3;             // 8B chunk (4 bf16) within 32B panel row
    const int b = offs[node], e = offs[node + 1];
    const short* hp = h1p + (long)panel * N * 16;
    float a0 = 0.f, a1 = 0.f, a2 = 0.f, a3 = 0.f;
    int i = b;
    const int e16 = b + (((e - b) >> 4) << 4);
    for (; i < e16; i += 16) {
        const int s = perm[i + g];
        const uint2 u = *(const uint2*)(hp + (long)s * 16 + c * 4);
        a0 += ulo(u.x); a1 += uhi(u.x);
        a2 += ulo(u.y); a3 += uhi(u.y);
    }
    {   // tail < 16
        const int ii = i + g;
        uint2 u = {0u, 0u};
        if (ii < e) {
            const int s = perm[ii];
            u = *(const uint2*)(hp + (long)s * 16 + c * 4);
        }
        a0 += ulo(u.x); a1 += uhi(u.x);
        a2 += ulo(u.y); a3 += uhi(u.y);
    }
    #pragma unroll
    for (int m = 4; m < 64; m <<= 1) {
        a0 += __shfl_xor(a0, m);
        a1 += __shfl_xor(a1, m);
        a2 += __shfl_xor(a2, m);
        a3 += __shfl_xor(a3, m);
    }
    if (g == 0) {
        const float inv = 1.f / fmaxf(degf[node], 1.f);
        uint2 o;
        o.x = packbf2(a0 * inv, a1 * inv);
        o.y = packbf2(a2 * inv, a3 * inv);
        *(uint2*)(agg + (long)node * KDIM + panel * 16 + c * 4) = o;
    }
}

// conv2 tail: one wave per node; 8 edge-groups x 8 lanes x 16B (64-col g2 row).
// out[n] = log_softmax( sum_j g2[j]/max(deg,1) + r2[n] ), r2 bf16.
__global__ __launch_bounds__(256) void gather_out(
    const short* __restrict__ g2, const short* __restrict__ r2,
    const int* __restrict__ offs, const int* __restrict__ perm,
    const float* __restrict__ degf, float* __restrict__ out, int N)
{
    const int node = blockIdx.x * 4 + (threadIdx.x >> 6);
    if (node >= N) return;
    const int l = threadIdx.x & 63;
    const int g = l >> 3;            // edge group 0..7
    const int c = l & 7;             // 16B chunk within 64-col row
    const int b = offs[node], e = offs[node + 1];
    float acc[8] = {0.f, 0.f, 0.f, 0.f, 0.f, 0.f, 0.f, 0.f};
    int i = b;
    const int e16 = b + (((e - b) >> 4) << 4);
    for (; i < e16; i += 16) {
        const int s0 = perm[i + g], s1 = perm[i + 8 + g];
        const bf16x8 v0 = *(const bf16x8*)(g2 + (long)s0 * 64 + c * 8);
        const bf16x8 v1 = *(const bf16x8*)(g2 + (long)s1 * 64 + c * 8);
        #pragma unroll
        for (int q = 0; q < 8; ++q) acc[q] += bf2f(v0[q]) + bf2f(v1[q]);
    }
    {   // tail < 16
        const int i0 = i + g, i1 = i + 8 + g;
        bf16x8 v0 = {0, 0, 0, 0, 0, 0, 0, 0};
        bf16x8 v1 = {0, 0, 0, 0, 0, 0, 0, 0};
        if (i0 < e) v0 = *(const bf16x8*)(g2 + (long)perm[i0] * 64 + c * 8);
        if (i1 < e) v1 = *(const bf16x8*)(g2 + (long)perm[i1] * 64 + c * 8);
        #pragma unroll
        for (int q = 0; q < 8; ++q) acc[q] += bf2f(v0[q]) + bf2f(v1[q]);
    }
    #pragma unroll
    for (int q = 0; q < 8; ++q) {
        acc[q] += __shfl_xor(acc[q], 8);
        acc[q] += __shfl_xor(acc[q], 16);
        acc[q] += __shfl_xor(acc[q], 32);
    }
    const float inv = 1.f / fmaxf(degf[node], 1.f);
    const bf16x8 rv = *(const bf16x8*)(r2 + (long)node * 64 + c * 8);
    float v[8];
    #pragma unroll
    for (int q = 0; q < 8; ++q) v[q] = acc[q] * inv + bf2f(rv[q]);
    float m = v[0];
    #pragma unroll
    for (int q = 1; q < 8; ++q) m = fmaxf(m, v[q]);
    m = fmaxf(m, __shfl_xor(m, 1));
    m = fmaxf(m, __shfl_xor(m, 2));
    m = fmaxf(m, __shfl_xor(m, 4));
    float s = 0.f;
    #pragma unroll
    for (int q = 0; q < 8; ++q) s += expf(v[q] - m);
    s += __shfl_xor(s, 1);
    s += __shfl_xor(s, 2);
    s += __shfl_xor(s, 4);
    const float L = m + logf(s);
    if (g == 0) {
        float4 oa = make_float4(v[0] - L, v[1] - L, v[2] - L, v[3] - L);
        float4 ob = make_float4(v[4] - L, v[5] - L, v[6] - L, v[7] - L);
        *(float4*)(out + (long)node * 64 + c * 8) = oa;
        *(float4*)(out + (long)node * 64 + c * 8 + 4) = ob;
    }
}

// ---- GEMMs ----

// layer 1: h1p = relu(x(f32) @ Wlin^T + b) -> bf16 PANEL layout [8][N][16].
__global__ __launch_bounds__(256) void gemm_lin(
    const float* __restrict__ X, const short* __restrict__ wpA,
    const float* __restrict__ bias, short* __restrict__ h1p, int N)
{
    __shared__ __attribute__((aligned(16))) short xa[64 * KDIM];
    const int t = threadIdx.x;
    const int w = t >> 6, lane = t & 63;
    const int row0 = blockIdx.x * 64;
    const int cf0 = w * 2;

    bf16x8 bwA[4][2];
    #pragma unroll
    for (int ks = 0; ks < 4; ++ks)
        #pragma unroll
        for (int c = 0; c < 2; ++c)
            bwA[ks][c] = *(const bf16x8*)(wpA + (((ks * 8) + cf0 + c) * 64 + lane) * 8);

    #pragma unroll
    for (int j = 0; j < 4; ++j) {
        const int sl = t + 256 * j;          // 0..1023
        const int r = sl >> 4, s = sl & 15;
        const int gg = s ^ (r & 7);
        const int grow = min(row0 + r, N - 1);
        const float4 f0 = *(const float4*)(X + (long)grow * KDIM + gg * 8);
        const float4 f1 = *(const float4*)(X + (long)grow * KDIM + gg * 8 + 4);
        uint4 o;
        o.x = packbf2(f0.x, f0.y); o.y = packbf2(f0.z, f0.w);
        o.z = packbf2(f1.x, f1.y); o.w = packbf2(f1.z, f1.w);
        *(uint4*)(xa + r * KDIM + s * 8) = o;
    }

    f32x4 acc[4][2];
    #pragma unroll
    for (int c = 0; c < 2; ++c) {
        const float bv = bias[(cf0 + c) * 16 + (lane & 15)];
        #pragma unroll
        for (int rf = 0; rf < 4; ++rf)
            acc[rf][c] = f32x4{bv, bv, bv, bv};
    }

    __syncthreads();

    #pragma unroll
    for (int ks = 0; ks < 4; ++ks) {
        #pragma unroll
        for (int rf = 0; rf < 4; ++rf) {
            const int rl = rf * 16 + (lane & 15);
            const int s = (ks * 4 + (lane >> 4)) ^ (rl & 7);
            const bf16x8 a = *(const bf16x8*)(xa + rl * KDIM + s * 8);
            #pragma unroll
            for (int c = 0; c < 2; ++c)
                acc[rf][c] = __builtin_amdgcn_mfma_f32_16x16x32_bf16(
                    a, bwA[ks][c], acc[rf][c], 0, 0, 0);
        }
    }

    #pragma unroll
    for (int rf = 0; rf < 4; ++rf)
        #pragma unroll
        for (int c = 0; c < 2; ++c)
            #pragma unroll
            for (int q = 0; q < 4; ++q) {
                const int row = row0 + rf * 16 + (lane >> 4) * 4 + q;
                if (row < N)
                    h1p[((long)(cf0 + c) * N + row) * 16 + (lane & 15)] =
                        (short)f2bf_u(fmaxf(acc[rf][c][q], 0.f));
            }
}

// conv1: out = relu( A @ WA^T + bias + B @ WB^T ). A = agg (row-major bf16),
// B = h1 in PANEL layout [8][N][16].
__global__ __launch_bounds__(256) void gemm_c1(
    const short* __restrict__ A, const short* __restrict__ h1p,
    const short* __restrict__ wpA, const short* __restrict__ wpB,
    const float* __restrict__ bias, short* __restrict__ out, int N)
{
    __shared__ __attribute__((aligned(16))) short xa[64 * KDIM];
    __shared__ __attribute__((aligned(16))) short xb[64 * KDIM];

    const int t = threadIdx.x;
    const int w = t >> 6, lane = t & 63;
    const int row0 = blockIdx.x * 64;
    const int cf0 = w * 2;

    bf16x8 bwA[4][2], bwB[4][2];
    #pragma unroll
    for (int ks = 0; ks < 4; ++ks)
        #pragma unroll
        for (int c = 0; c < 2; ++c) {
            bwA[ks][c] = *(const bf16x8*)(wpA + (((ks * 8) + cf0 + c) * 64 + lane) * 8);
            bwB[ks][c] = *(const bf16x8*)(wpB + (((ks * 8) + cf0 + c) * 64 + lane) * 8);
        }

    #pragma unroll
    for (int ii = 0; ii < 4; ++ii) {
        const int i = w * 4 + ii;
        const int rl = i * 4 + (lane >> 4);
        const int grow = min(row0 + rl, N - 1);
        const int gs = (lane & 15) ^ (rl & 7);
        gload_lds16(A + (long)grow * KDIM + gs * 8, &xa[i * 512]);
        // h1 panel layout: granule gs = cols gs*8..gs*8+7 -> panel gs>>1, half gs&1
        gload_lds16(h1p + ((long)(gs >> 1) * N + grow) * 16 + (gs & 1) * 8,
                    &xb[i * 512]);
    }

    f32x4 acc[4][2];
    #pragma unroll
    for (int c = 0; c < 2; ++c) {
        const float bv = bias[(cf0 + c) * 16 + (lane & 15)];
        #pragma unroll
        for (int rf = 0; rf < 4; ++rf)
            acc[rf][c] = f32x4{bv, bv, bv, bv};
    }

    __syncthreads();

    #pragma unroll
    for (int ks = 0; ks < 4; ++ks) {
        #pragma unroll
        for (int rf = 0; rf < 4; ++rf) {
            const int rl = rf * 16 + (lane & 15);
            const int s = (ks * 4 + (lane >> 4)) ^ (rl & 7);
            const bf16x8 a = *(const bf16x8*)(xa + rl * KDIM + s * 8);
            #pragma unroll
            for (int c = 0; c < 2; ++c)
                acc[rf][c] = __builtin_amdgcn_mfma_f32_16x16x32_bf16(
                    a, bwA[ks][c], acc[rf][c], 0, 0, 0);
            const bf16x8 bb = *(const bf16x8*)(xb + rl * KDIM + s * 8);
            #pragma unroll
            for (int c = 0; c < 2; ++c)
                acc[rf][c] = __builtin_amdgcn_mfma_f32_16x16x32_bf16(
                    bb, bwB[ks][c], acc[rf][c], 0, 0, 0);
        }
    }

    #pragma unroll
    for (int rf = 0; rf < 4; ++rf)
        #pragma unroll
        for (int c = 0; c < 2; ++c)
            #pragma unroll
            for (int q = 0; q < 4; ++q) {
                const int row = row0 + rf * 16 + (lane >> 4) * 4 + q;
                if (row < N)
                    out[(long)row * KDIM + (cf0 + c) * 16 + (lane & 15)] =
                        (short)f2bf_u(fmaxf(acc[rf][c][q], 0.f));
            }
}

// conv2 dual GEMM: g2 = A @ Wl^T (bf16), r2 = A @ Wr^T + b (bf16).
__global__ __launch_bounds__(256) void gemm_dual(
    const short* __restrict__ A, const short* __restrict__ wpL,
    const short* __restrict__ wpR, const float* __restrict__ bias,
    short* __restrict__ g2, short* __restrict__ r2, int N)
{
    __shared__ __attribute__((aligned(16))) short xa[64 * KDIM];
    const int t = threadIdx.x;
    const int w = t >> 6, lane = t & 63;
    const int row0 = blockIdx.x * 64;
    const int side = w >> 1;
    const int cf0 = (w & 1) * 2;
    const short* wpS = side ? wpR : wpL;

    bf16x8 bw[4][2];
    #pragma unroll
    for (int ks = 0; ks < 4; ++ks)
        #pragma unroll
        for (int c = 0; c < 2; ++c)
            bw[ks][c] = *(const bf16x8*)(wpS + (((ks * 4) + cf0 + c) * 64 + lane) * 8);

    #pragma unroll
    for (int ii = 0; ii < 4; ++ii) {
        const int i = w * 4 + ii;
        const int rl = i * 4 + (lane >> 4);
        const int grow = min(row0 + rl, N - 1);
        const int gs = (lane & 15) ^ (rl & 7);
        gload_lds16(A + (long)grow * KDIM + gs * 8, &xa[i * 512]);
    }

    f32x4 acc[4][2];
    #pragma unroll
    for (int c = 0; c < 2; ++c) {
        const float bv = side ? bias[(cf0 + c) * 16 + (lane & 15)] : 0.f;
        #pragma unroll
        for (int rf = 0; rf < 4; ++rf)
            acc[rf][c] = f32x4{bv, bv, bv, bv};
    }

    __syncthreads();

    #pragma unroll
    for (int ks = 0; ks < 4; ++ks) {
        #pragma unroll
        for (int rf = 0; rf < 4; ++rf) {
            const int rl = rf * 16 + (lane & 15);
            const int s = (ks * 4 + (lane >> 4)) ^ (rl & 7);
            const bf16x8 a = *(const bf16x8*)(xa + rl * KDIM + s * 8);
            #pragma unroll
            for (int c = 0; c < 2; ++c)
                acc[rf][c] = __builtin_amdgcn_mfma_f32_16x16x32_bf16(
                    a, bw[ks][c], acc[rf][c], 0, 0, 0);
        }
    }

    short* dst = side ? r2 : g2;
    #pragma unroll
    for (int rf = 0; rf < 4; ++rf)
        #pragma unroll
        for (int c = 0; c < 2; ++c)
            #pragma unroll
            for (int q = 0; q < 4; ++q) {
                const int row = row0 + rf * 16 + (lane >> 4) * 4 + q;
                if (row < N)
                    dst[(long)row * 64 + (cf0 + c) * 16 + (lane & 15)] =
                        (short)f2bf_u(acc[rf][c][q]);
            }
}

extern "C" void kernel_launch(void* const* d_in, const int* in_sizes, int n_in,
                              void* d_out, int out_size, void* d_ws, size_t ws_size,
                              hipStream_t stream) {
    const float* x     = (const float*)d_in[0];
    const int*   ei    = (const int*)d_in[1];
    const float* lin_W = (const float*)d_in[2];
    const float* lin_b = (const float*)d_in[3];
    const float* c1_Wl = (const float*)d_in[4];
    const float* c1_bl = (const float*)d_in[5];
    const float* c1_Wr = (const float*)d_in[6];
    const float* c2_Wl = (const float*)d_in[7];
    const float* c2_bl = (const float*)d_in[8];
    const float* c2_Wr = (const float*)d_in[9];
    float* out = (float*)d_out;

    const int N = in_sizes[0] / KDIM;
    const int E = in_sizes[1] / 2;

    short* h1p  = (short*)d_ws;                  // [8][N][16] bf16 panels
    short* h2   = h1p + (size_t)N * KDIM;        // N*128 bf16
    short* aggb = h2 + (size_t)N * KDIM;         // N*128 bf16
    short* g2   = aggb + (size_t)N * KDIM;       // N*64 bf16
    short* r2   = g2 + (size_t)N * 64;           // N*64 bf16
    short* wp   = r2 + (size_t)N * 64;           // 65536 bf16
    float* degf = (float*)(wp + 65536);          // N f32
    int* offs   = (int*)(degf + N);              // N+1
    const int nwg = (E + CH - 1) / CH;           // 98
    const int NB  = (N + 255) >> BSH;            // 391
    int* hist   = offs + (N + 1);                // NB*nwg
    int* bsum   = hist + NB * nwg;               // 256
    unsigned* packed = (unsigned*)(bsum + 256);  // E
    int* perm   = (int*)(packed + E);            // E

    const int nb = (N + 63) / 64;
    const int gb = (N + 3) / 4;
    const int gpb = 8 * ((N + 3) / 4);           // panelized gather blocks
    const int nh = NB * nwg;
    const int nsb = (nh + 1023) / 1024;

    // ---- CSR build: two-level multisplit (no global atomics) ----
    bin_hist<<<nwg, 256, 0, stream>>>(ei, hist, E, nwg, NB);
    greduce<<<nsb, 256, 0, stream>>>(hist, bsum, nh);
    scan_bsums<<<1, 256, 0, stream>>>(bsum, nsb);
    gapply<<<nsb, 256, 0, stream>>>(hist, bsum, nh);
    bin_scatter<<<nwg, 256, 0, stream>>>(ei, hist, packed, E, nwg, NB);
    bucket_sort<<<NB, 256, 0, stream>>>(packed, hist, offs, degf, perm, E, nwg, NB, N);

    pack_weights<<<256, 256, 0, stream>>>(lin_W, c1_Wl, c1_Wr, c2_Wl, c2_Wr, wp);

    // layer 1: h1p = relu(x @ lin_W^T + lin_b)  (panel layout)
    gemm_lin<<<nb, 256, 0, stream>>>(x, wp, lin_b, h1p, N);

    // conv1: agg = mean_{j->i} h1[j] (XCD-panelized);
    //        h2 = relu(agg @ Wl^T + b + h1 @ Wr^T)
    gather_mean_panel<<<gpb, 256, 0, stream>>>(h1p, offs, perm, degf, aggb, N);
    gemm_c1<<<nb, 256, 0, stream>>>(aggb, h1p, wp + 16384, wp + 32768, c1_bl, h2, N);

    // conv2: g2 = h2 @ Wl^T, r2 = h2 @ Wr^T + b (both bf16);
    // out = log_softmax(gather_mean(g2) + r2)
    gemm_dual<<<nb, 256, 0, stream>>>(h2, wp + 49152, wp + 57344, c2_bl, g2, r2, N);
    gather_out<<<gb, 256, 0, stream>>>(g2, r2, offs, perm, degf, out, N);
}

// Round 9
// 187.357 us; speedup vs baseline: 2.0013x; 2.0013x over previous
//
#include <hip/hip_runtime.h>

// GraphSAGE forward: lin+relu -> SAGEConv(mean)+relu -> SAGEConv(mean) -> log_softmax
// N=100000, E=1.6M, dims 128 -> 128 -> 128 -> 64.
//
// Round 9: panel experiment reverted (cross-XCD false sharing + 8x wave overhead).
// (a) gather_mean_128 = round-7 version (row-major h1, 16B loads, branch-free);
// (b) CSR chunks CH 16384->4096 (391 blocks for bin_hist/bin_scatter);
// (c) gemm_c1 + gemm_dual fused -> gemm_c1c2: conv1 tile relu'd in regs, staged
//     to LDS (bf16, swizzled), conv2 dual GEMM in-kernel; h2 buffer eliminated.

#define KDIM 128
#define CH 4096             // edges per multisplit chunk (391 chunks)
#define BSH 8               // bucket = dst >> 8 (256 nodes/bucket)
#define BCAP 8192           // per-bucket LDS capacity (avg ~4100)

using bf16x8 = __attribute__((ext_vector_type(8))) short;
using f32x4  = __attribute__((ext_vector_type(4))) float;

__device__ __forceinline__ unsigned short f2bf_u(float f) {
    unsigned u = __float_as_uint(f);
    u += 0x7fffu + ((u >> 16) & 1u);
    return (unsigned short)(u >> 16);
}
__device__ __forceinline__ unsigned packbf2(float a, float b) {
    return (unsigned)f2bf_u(a) | ((unsigned)f2bf_u(b) << 16);
}
__device__ __forceinline__ float bf2f(short s) {
    return __uint_as_float(((unsigned)(unsigned short)s) << 16);
}

__device__ __forceinline__ void gload_lds16(const short* g, short* l) {
    __builtin_amdgcn_global_load_lds(
        (const __attribute__((address_space(1))) unsigned int*)g,
        (__attribute__((address_space(3))) unsigned int*)l, 16, 0, 0);
}

// ---- multisplit CSR build ----

__global__ __launch_bounds__(256) void bin_hist(
    const int* __restrict__ ei, int* __restrict__ hist, int E, int nwg, int NB)
{
    __shared__ int lh[512];
    const int w = blockIdx.x, t = threadIdx.x;
    for (int b = t; b < NB; b += 256) lh[b] = 0;
    __syncthreads();
    const int e0 = w * CH, e1 = min(E, e0 + CH);
    for (int e = e0 + t; e < e1; e += 256)
        atomicAdd(&lh[ei[E + e] >> BSH], 1);
    __syncthreads();
    for (int b = t; b < NB; b += 256) hist[b * nwg + w] = lh[b];
}

__global__ __launch_bounds__(256) void greduce(
    const int* __restrict__ in, int* __restrict__ bsum, int n)
{
    const int t = threadIdx.x;
    const int idx = blockIdx.x * 1024 + t * 4;
    int s = 0;
    if (idx + 4 <= n) {
        int4 a = *(const int4*)(in + idx);
        s = a.x + a.y + a.z + a.w;
    } else {
        #pragma unroll
        for (int k = 0; k < 4; ++k) if (idx + k < n) s += in[idx + k];
    }
    #pragma unroll
    for (int d = 1; d < 64; d <<= 1) s += __shfl_xor(s, d);
    __shared__ int ws[4];
    if ((t & 63) == 0) ws[t >> 6] = s;
    __syncthreads();
    if (t == 0) bsum[blockIdx.x] = ws[0] + ws[1] + ws[2] + ws[3];
}

__global__ __launch_bounds__(256) void scan_bsums(int* __restrict__ bsum, int nb)
{
    const int t = threadIdx.x;
    const int lane = t & 63, wid = t >> 6;
    int v = (t < nb) ? bsum[t] : 0;
    int incl = v;
    #pragma unroll
    for (int d = 1; d < 64; d <<= 1) {
        int u = __shfl_up(incl, d);
        if (lane >= d) incl += u;
    }
    __shared__ int ws[4];
    if (lane == 63) ws[wid] = incl;
    __syncthreads();
    int woff = 0;
    #pragma unroll
    for (int w = 0; w < 4; ++w) if (w < wid) woff += ws[w];
    const int excl = woff + incl - v;
    if (t <= nb) bsum[t] = excl;
}

__global__ __launch_bounds__(256) void gapply(
    int* __restrict__ io, const int* __restrict__ bsum, int n)
{
    const int t = threadIdx.x;
    const int lane = t & 63, wid = t >> 6;
    const int idx = blockIdx.x * 1024 + t * 4;
    int v[4] = {0, 0, 0, 0};
    if (idx + 4 <= n) {
        int4 a = *(const int4*)(io + idx);
        v[0] = a.x; v[1] = a.y; v[2] = a.z; v[3] = a.w;
    } else {
        #pragma unroll
        for (int k = 0; k < 4; ++k) if (idx + k < n) v[k] = io[idx + k];
    }
    const int sum = v[0] + v[1] + v[2] + v[3];
    int incl = sum;
    #pragma unroll
    for (int d = 1; d < 64; d <<= 1) {
        int u = __shfl_up(incl, d);
        if (lane >= d) incl += u;
    }
    __shared__ int ws[4];
    if (lane == 63) ws[wid] = incl;
    __syncthreads();
    int woff = 0;
    #pragma unroll
    for (int w = 0; w < 4; ++w) if (w < wid) woff += ws[w];
    int excl = bsum[blockIdx.x] + woff + (incl - sum);
    if (idx + 4 <= n) {
        int4 o;
        o.x = excl; o.y = excl + v[0]; o.z = excl + v[0] + v[1];
        o.w = excl + v[0] + v[1] + v[2];
        *(int4*)(io + idx) = o;
    } else {
        #pragma unroll
        for (int k = 0; k < 4; ++k) {
            if (idx + k < n) { io[idx + k] = excl; excl += v[k]; }
        }
    }
}

__global__ __launch_bounds__(256) void bin_scatter(
    const int* __restrict__ ei, const int* __restrict__ hist_s,
    unsigned* __restrict__ packed, int E, int nwg, int NB)
{
    __shared__ int lc[512];
    const int w = blockIdx.x, t = threadIdx.x;
    for (int b = t; b < NB; b += 256) lc[b] = hist_s[b * nwg + w];
    __syncthreads();
    const int e0 = w * CH, e1 = min(E, e0 + CH);
    for (int e = e0 + t; e < e1; e += 256) {
        const int src = ei[e];
        const int dst = ei[E + e];
        const int b = dst >> BSH;
        const int pos = atomicAdd(&lc[b], 1);
        packed[pos] = ((unsigned)(dst & 255) << 17) | (unsigned)src;
    }
}

__global__ __launch_bounds__(256) void bucket_sort(
    const unsigned* __restrict__ packed, const int* __restrict__ hist_s,
    int* __restrict__ offs, float* __restrict__ degf, int* __restrict__ perm,
    int E, int nwg, int NB, int N)
{
    __shared__ unsigned le[BCAP];
    __shared__ int lp[BCAP];
    __shared__ int lh[256], lx[256], lc[256];
    __shared__ int ws[4];
    const int b = blockIdx.x, t = threadIdx.x;
    const int bb = hist_s[b * nwg];
    const int be = (b + 1 < NB) ? hist_s[(b + 1) * nwg] : E;
    int cnt = be - bb;
    if (cnt > BCAP) cnt = BCAP;
    for (int i = t; i < cnt; i += 256) le[i] = packed[bb + i];
    lh[t] = 0;
    __syncthreads();
    for (int i = t; i < cnt; i += 256) atomicAdd(&lh[le[i] >> 17], 1);
    __syncthreads();
    const int lane = t & 63, wid = t >> 6;
    const int v = lh[t];
    int incl = v;
    #pragma unroll
    for (int d = 1; d < 64; d <<= 1) {
        int u = __shfl_up(incl, d);
        if (lane >= d) incl += u;
    }
    if (lane == 63) ws[wid] = incl;
    __syncthreads();
    int woff = 0;
    #pragma unroll
    for (int w = 0; w < 4; ++w) if (w < wid) woff += ws[w];
    const int excl = woff + incl - v;
    lx[t] = excl;
    lc[t] = excl;
    __syncthreads();
    for (int i = t; i < cnt; i += 256) {
        const unsigned p = le[i];
        const int pos = atomicAdd(&lc[p >> 17], 1);
        lp[pos] = (int)(p & 0x1FFFFu);
    }
    __syncthreads();
    for (int i = t; i < cnt; i += 256) perm[bb + i] = lp[i];
    const int node = (b << BSH) + t;
    if (node < N) {
        offs[node] = bb + lx[t];
        degf[node] = (float)v;
    }
    if (b == NB - 1 && t == 0) offs[N] = E;
}

// ---- operand prep ----

// wp[ks][cf][lane][j] = bf16(W[cf*16 + (lane&15)][ks*32 + (lane>>4)*8 + j])
__global__ __launch_bounds__(256) void pack_weights(
    const float* __restrict__ Wlin, const float* __restrict__ Wc1l,
    const float* __restrict__ Wc1r, const float* __restrict__ Wc2l,
    const float* __restrict__ Wc2r, short* __restrict__ wp)
{
    int idx = blockIdx.x * 256 + threadIdx.x;   // 0..65535
    if (idx >= 65536) return;
    const float* W; short* dst; int off, ncf;
    if (idx < 16384)      { W = Wlin; dst = wp;         off = idx;         ncf = 8; }
    else if (idx < 32768) { W = Wc1l; dst = wp + 16384; off = idx - 16384; ncf = 8; }
    else if (idx < 49152) { W = Wc1r; dst = wp + 32768; off = idx - 32768; ncf = 8; }
    else if (idx < 57344) { W = Wc2l; dst = wp + 49152; off = idx - 49152; ncf = 4; }
    else                  { W = Wc2r; dst = wp + 57344; off = idx - 57344; ncf = 4; }
    int j    = off & 7;
    int lane = (off >> 3) & 63;
    int cf   = (off >> 9) & (ncf - 1);
    int ks   = off >> ((ncf == 8) ? 12 : 11);
    int m = cf * 16 + (lane & 15);
    int k = ks * 32 + ((lane >> 4) << 3) + j;
    dst[off] = (short)f2bf_u(W[m * KDIM + k]);
}

// ---- gathers ----

// conv1: one wave per node; 4 edge-groups x 16 lanes x 16B (full 128-col row).
// Branch-free 16-edge main loop; predicated tail. agg[n] = bf16(sum/max(deg,1)).
__global__ __launch_bounds__(256) void gather_mean_128(
    const short* __restrict__ h, const int* __restrict__ offs,
    const int* __restrict__ perm, const float* __restrict__ degf,
    short* __restrict__ agg, int N)
{
    const int node = blockIdx.x * 4 + (threadIdx.x >> 6);
    if (node >= N) return;
    const int l = threadIdx.x & 63;
    const int g = l >> 4;            // edge group 0..3
    const int c = l & 15;            // 16B chunk within row
    const int b = offs[node], e = offs[node + 1];
    float acc[8] = {0.f, 0.f, 0.f, 0.f, 0.f, 0.f, 0.f, 0.f};
    int i = b;
    const int e16 = b + (((e - b) >> 4) << 4);
    for (; i < e16; i += 16) {
        const int s0 = perm[i + g],     s1 = perm[i + 4 + g];
        const int s2 = perm[i + 8 + g], s3 = perm[i + 12 + g];
        const bf16x8 v0 = *(const bf16x8*)(h + (long)s0 * KDIM + c * 8);
        const bf16x8 v1 = *(const bf16x8*)(h + (long)s1 * KDIM + c * 8);
        const bf16x8 v2 = *(const bf16x8*)(h + (long)s2 * KDIM + c * 8);
        const bf16x8 v3 = *(const bf16x8*)(h + (long)s3 * KDIM + c * 8);
        #pragma unroll
        for (int q = 0; q < 8; ++q)
            acc[q] += (bf2f(v0[q]) + bf2f(v1[q])) + (bf2f(v2[q]) + bf2f(v3[q]));
    }
    if (i + 8 <= e) {
        const int s0 = perm[i + g], s1 = perm[i + 4 + g];
        const bf16x8 v0 = *(const bf16x8*)(h + (long)s0 * KDIM + c * 8);
        const bf16x8 v1 = *(const bf16x8*)(h + (long)s1 * KDIM + c * 8);
        #pragma unroll
        for (int q = 0; q < 8; ++q) acc[q] += bf2f(v0[q]) + bf2f(v1[q]);
        i += 8;
    }
    {   // tail < 8
        const int i0 = i + g, i1 = i + 4 + g;
        bf16x8 v0 = {0, 0, 0, 0, 0, 0, 0, 0};
        bf16x8 v1 = {0, 0, 0, 0, 0, 0, 0, 0};
        if (i0 < e) v0 = *(const bf16x8*)(h + (long)perm[i0] * KDIM + c * 8);
        if (i1 < e) v1 = *(const bf16x8*)(h + (long)perm[i1] * KDIM + c * 8);
        #pragma unroll
        for (int q = 0; q < 8; ++q) acc[q] += bf2f(v0[q]) + bf2f(v1[q]);
    }
    #pragma unroll
    for (int q = 0; q < 8; ++q) {
        acc[q] += __shfl_xor(acc[q], 16);
        acc[q] += __shfl_xor(acc[q], 32);
    }
    if (g == 0) {
        const float inv = 1.f / fmaxf(degf[node], 1.f);
        uint4 o;
        o.x = packbf2(acc[0] * inv, acc[1] * inv);
        o.y = packbf2(acc[2] * inv, acc[3] * inv);
        o.z = packbf2(acc[4] * inv, acc[5] * inv);
        o.w = packbf2(acc[6] * inv, acc[7] * inv);
        *(uint4*)(agg + (long)node * KDIM + c * 8) = o;
    }
}

// conv2 tail: one wave per node; 8 edge-groups x 8 lanes x 16B (64-col g2 row).
// out[n] = log_softmax( sum_j g2[j]/max(deg,1) + r2[n] ), r2 bf16.
__global__ __launch_bounds__(256) void gather_out(
    const short* __restrict__ g2, const short* __restrict__ r2,
    const int* __restrict__ offs, const int* __restrict__ perm,
    const float* __restrict__ degf, float* __restrict__ out, int N)
{
    const int node = blockIdx.x * 4 + (threadIdx.x >> 6);
    if (node >= N) return;
    const int l = threadIdx.x & 63;
    const int g = l >> 3;            // edge group 0..7
    const int c = l & 7;             // 16B chunk within 64-col row
    const int b = offs[node], e = offs[node + 1];
    float acc[8] = {0.f, 0.f, 0.f, 0.f, 0.f, 0.f, 0.f, 0.f};
    int i = b;
    const int e16 = b + (((e - b) >> 4) << 4);
    for (; i < e16; i += 16) {
        const int s0 = perm[i + g], s1 = perm[i + 8 + g];
        const bf16x8 v0 = *(const bf16x8*)(g2 + (long)s0 * 64 + c * 8);
        const bf16x8 v1 = *(const bf16x8*)(g2 + (long)s1 * 64 + c * 8);
        #pragma unroll
        for (int q = 0; q < 8; ++q) acc[q] += bf2f(v0[q]) + bf2f(v1[q]);
    }
    {   // tail < 16
        const int i0 = i + g, i1 = i + 8 + g;
        bf16x8 v0 = {0, 0, 0, 0, 0, 0, 0, 0};
        bf16x8 v1 = {0, 0, 0, 0, 0, 0, 0, 0};
        if (i0 < e) v0 = *(const bf16x8*)(g2 + (long)perm[i0] * 64 + c * 8);
        if (i1 < e) v1 = *(const bf16x8*)(g2 + (long)perm[i1] * 64 + c * 8);
        #pragma unroll
        for (int q = 0; q < 8; ++q) acc[q] += bf2f(v0[q]) + bf2f(v1[q]);
    }
    #pragma unroll
    for (int q = 0; q < 8; ++q) {
        acc[q] += __shfl_xor(acc[q], 8);
        acc[q] += __shfl_xor(acc[q], 16);
        acc[q] += __shfl_xor(acc[q], 32);
    }
    const float inv = 1.f / fmaxf(degf[node], 1.f);
    const bf16x8 rv = *(const bf16x8*)(r2 + (long)node * 64 + c * 8);
    float v[8];
    #pragma unroll
    for (int q = 0; q < 8; ++q) v[q] = acc[q] * inv + bf2f(rv[q]);
    float m = v[0];
    #pragma unroll
    for (int q = 1; q < 8; ++q) m = fmaxf(m, v[q]);
    m = fmaxf(m, __shfl_xor(m, 1));
    m = fmaxf(m, __shfl_xor(m, 2));
    m = fmaxf(m, __shfl_xor(m, 4));
    float s = 0.f;
    #pragma unroll
    for (int q = 0; q < 8; ++q) s += expf(v[q] - m);
    s += __shfl_xor(s, 1);
    s += __shfl_xor(s, 2);
    s += __shfl_xor(s, 4);
    const float L = m + logf(s);
    if (g == 0) {
        float4 oa = make_float4(v[0] - L, v[1] - L, v[2] - L, v[3] - L);
        float4 ob = make_float4(v[4] - L, v[5] - L, v[6] - L, v[7] - L);
        *(float4*)(out + (long)node * 64 + c * 8) = oa;
        *(float4*)(out + (long)node * 64 + c * 8 + 4) = ob;
    }
}

// ---- GEMMs ----

// layer 1: h1 = relu(x(f32) @ Wlin^T + b) -> bf16 row-major. Stages f32 directly.
__global__ __launch_bounds__(256) void gemm_lin(
    const float* __restrict__ X, const short* __restrict__ wpA,
    const float* __restrict__ bias, short* __restrict__ out, int N)
{
    __shared__ __attribute__((aligned(16))) short xa[64 * KDIM];
    const int t = threadIdx.x;
    const int w = t >> 6, lane = t & 63;
    const int row0 = blockIdx.x * 64;
    const int cf0 = w * 2;

    bf16x8 bwA[4][2];
    #pragma unroll
    for (int ks = 0; ks < 4; ++ks)
        #pragma unroll
        for (int c = 0; c < 2; ++c)
            bwA[ks][c] = *(const bf16x8*)(wpA + (((ks * 8) + cf0 + c) * 64 + lane) * 8);

    #pragma unroll
    for (int j = 0; j < 4; ++j) {
        const int sl = t + 256 * j;          // 0..1023
        const int r = sl >> 4, s = sl & 15;
        const int gg = s ^ (r & 7);
        const int grow = min(row0 + r, N - 1);
        const float4 f0 = *(const float4*)(X + (long)grow * KDIM + gg * 8);
        const float4 f1 = *(const float4*)(X + (long)grow * KDIM + gg * 8 + 4);
        uint4 o;
        o.x = packbf2(f0.x, f0.y); o.y = packbf2(f0.z, f0.w);
        o.z = packbf2(f1.x, f1.y); o.w = packbf2(f1.z, f1.w);
        *(uint4*)(xa + r * KDIM + s * 8) = o;
    }

    f32x4 acc[4][2];
    #pragma unroll
    for (int c = 0; c < 2; ++c) {
        const float bv = bias[(cf0 + c) * 16 + (lane & 15)];
        #pragma unroll
        for (int rf = 0; rf < 4; ++rf)
            acc[rf][c] = f32x4{bv, bv, bv, bv};
    }

    __syncthreads();

    #pragma unroll
    for (int ks = 0; ks < 4; ++ks) {
        #pragma unroll
        for (int rf = 0; rf < 4; ++rf) {
            const int rl = rf * 16 + (lane & 15);
            const int s = (ks * 4 + (lane >> 4)) ^ (rl & 7);
            const bf16x8 a = *(const bf16x8*)(xa + rl * KDIM + s * 8);
            #pragma unroll
            for (int c = 0; c < 2; ++c)
                acc[rf][c] = __builtin_amdgcn_mfma_f32_16x16x32_bf16(
                    a, bwA[ks][c], acc[rf][c], 0, 0, 0);
        }
    }

    #pragma unroll
    for (int rf = 0; rf < 4; ++rf)
        #pragma unroll
        for (int c = 0; c < 2; ++c)
            #pragma unroll
            for (int q = 0; q < 4; ++q) {
                const int row = row0 + rf * 16 + (lane >> 4) * 4 + q;
                if (row < N)
                    out[(long)row * KDIM + (cf0 + c) * 16 + (lane & 15)] =
                        (short)f2bf_u(fmaxf(acc[rf][c][q], 0.f));
            }
}

// Fused conv1+conv2 GEMMs:
//   phase 1: t = relu( agg @ Wl1^T + b1 + h1 @ Wr1^T )   (64x128 tile, in regs)
//   stage t -> LDS (bf16, phase-1 swizzle layout), barrier
//   phase 2: g2 = t @ Wl2^T (bf16), r2 = t @ Wr2^T + b2 (bf16)
// h2 never touches global memory.
__global__ __launch_bounds__(256) void gemm_c1c2(
    const short* __restrict__ A, const short* __restrict__ B,
    const short* __restrict__ wpA, const short* __restrict__ wpB,
    const short* __restrict__ wpL2, const short* __restrict__ wpR2,
    const float* __restrict__ bias1, const float* __restrict__ bias2,
    short* __restrict__ g2, short* __restrict__ r2, int N)
{
    __shared__ __attribute__((aligned(16))) short xa[64 * KDIM];
    __shared__ __attribute__((aligned(16))) short xb[64 * KDIM];

    const int t = threadIdx.x;
    const int w = t >> 6, lane = t & 63;
    const int row0 = blockIdx.x * 64;
    const int cf0 = w * 2;

    bf16x8 bwA[4][2], bwB[4][2];
    #pragma unroll
    for (int ks = 0; ks < 4; ++ks)
        #pragma unroll
        for (int c = 0; c < 2; ++c) {
            bwA[ks][c] = *(const bf16x8*)(wpA + (((ks * 8) + cf0 + c) * 64 + lane) * 8);
            bwB[ks][c] = *(const bf16x8*)(wpB + (((ks * 8) + cf0 + c) * 64 + lane) * 8);
        }

    #pragma unroll
    for (int ii = 0; ii < 4; ++ii) {
        const int i = w * 4 + ii;
        const int rl = i * 4 + (lane >> 4);
        const int grow = min(row0 + rl, N - 1);
        const int gs = (lane & 15) ^ (rl & 7);
        gload_lds16(A + (long)grow * KDIM + gs * 8, &xa[i * 512]);
        gload_lds16(B + (long)grow * KDIM + gs * 8, &xb[i * 512]);
    }

    f32x4 acc[4][2];
    #pragma unroll
    for (int c = 0; c < 2; ++c) {
        const float bv = bias1[(cf0 + c) * 16 + (lane & 15)];
        #pragma unroll
        for (int rf = 0; rf < 4; ++rf)
            acc[rf][c] = f32x4{bv, bv, bv, bv};
    }

    __syncthreads();

    #pragma unroll
    for (int ks = 0; ks < 4; ++ks) {
        #pragma unroll
        for (int rf = 0; rf < 4; ++rf) {
            const int rl = rf * 16 + (lane & 15);
            const int s = (ks * 4 + (lane >> 4)) ^ (rl & 7);
            const bf16x8 a = *(const bf16x8*)(xa + rl * KDIM + s * 8);
            #pragma unroll
            for (int c = 0; c < 2; ++c)
                acc[rf][c] = __builtin_amdgcn_mfma_f32_16x16x32_bf16(
                    a, bwA[ks][c], acc[rf][c], 0, 0, 0);
            const bf16x8 bb = *(const bf16x8*)(xb + rl * KDIM + s * 8);
            #pragma unroll
            for (int c = 0; c < 2; ++c)
                acc[rf][c] = __builtin_amdgcn_mfma_f32_16x16x32_bf16(
                    bb, bwB[ks][c], acc[rf][c], 0, 0, 0);
        }
    }

    // ---- stage relu(t) into xa (bf16, same swizzle as phase-1 layout) ----
    __syncthreads();   // all waves done reading xa/xb
    #pragma unroll
    for (int rf = 0; rf < 4; ++rf)
        #pragma unroll
        for (int c = 0; c < 2; ++c)
            #pragma unroll
            for (int q = 0; q < 4; ++q) {
                const int r = rf * 16 + (lane >> 4) * 4 + q;
                const int col = (cf0 + c) * 16 + (lane & 15);
                const int s = col >> 3;
                xa[r * KDIM + ((s ^ (r & 7)) << 3) + (col & 7)] =
                    (short)f2bf_u(fmaxf(acc[rf][c][q], 0.f));
            }

    // ---- phase 2: dual 128->64 GEMM from LDS tile ----
    const int side = w >> 1;            // 0 -> g2 (Wl2), 1 -> r2 (Wr2 + b2)
    const int cf2 = (w & 1) * 2;
    const short* wp2 = side ? wpR2 : wpL2;

    bf16x8 bw2[4][2];
    #pragma unroll
    for (int ks = 0; ks < 4; ++ks)
        #pragma unroll
        for (int c = 0; c < 2; ++c)
            bw2[ks][c] = *(const bf16x8*)(wp2 + (((ks * 4) + cf2 + c) * 64 + lane) * 8);

    f32x4 acc2[4][2];
    #pragma unroll
    for (int c = 0; c < 2; ++c) {
        const float bv = side ? bias2[(cf2 + c) * 16 + (lane & 15)] : 0.f;
        #pragma unroll
        for (int rf = 0; rf < 4; ++rf)
            acc2[rf][c] = f32x4{bv, bv, bv, bv};
    }

    __syncthreads();

    #pragma unroll
    for (int ks = 0; ks < 4; ++ks) {
        #pragma unroll
        for (int rf = 0; rf < 4; ++rf) {
            const int rl = rf * 16 + (lane & 15);
            const int s = (ks * 4 + (lane >> 4)) ^ (rl & 7);
            const bf16x8 a = *(const bf16x8*)(xa + rl * KDIM + s * 8);
            #pragma unroll
            for (int c = 0; c < 2; ++c)
                acc2[rf][c] = __builtin_amdgcn_mfma_f32_16x16x32_bf16(
                    a, bw2[ks][c], acc2[rf][c], 0, 0, 0);
        }
    }

    short* dst = side ? r2 : g2;
    #pragma unroll
    for (int rf = 0; rf < 4; ++rf)
        #pragma unroll
        for (int c = 0; c < 2; ++c)
            #pragma unroll
            for (int q = 0; q < 4; ++q) {
                const int row = row0 + rf * 16 + (lane >> 4) * 4 + q;
                if (row < N)
                    dst[(long)row * 64 + (cf2 + c) * 16 + (lane & 15)] =
                        (short)f2bf_u(acc2[rf][c][q]);
            }
}

extern "C" void kernel_launch(void* const* d_in, const int* in_sizes, int n_in,
                              void* d_out, int out_size, void* d_ws, size_t ws_size,
                              hipStream_t stream) {
    const float* x     = (const float*)d_in[0];
    const int*   ei    = (const int*)d_in[1];
    const float* lin_W = (const float*)d_in[2];
    const float* lin_b = (const float*)d_in[3];
    const float* c1_Wl = (const float*)d_in[4];
    const float* c1_bl = (const float*)d_in[5];
    const float* c1_Wr = (const float*)d_in[6];
    const float* c2_Wl = (const float*)d_in[7];
    const float* c2_bl = (const float*)d_in[8];
    const float* c2_Wr = (const float*)d_in[9];
    float* out = (float*)d_out;

    const int N = in_sizes[0] / KDIM;
    const int E = in_sizes[1] / 2;

    short* h1   = (short*)d_ws;                  // N*128 bf16
    short* aggb = h1 + (size_t)N * KDIM;         // N*128 bf16
    short* g2   = aggb + (size_t)N * KDIM;       // N*64 bf16
    short* r2   = g2 + (size_t)N * 64;           // N*64 bf16
    short* wp   = r2 + (size_t)N * 64;           // 65536 bf16
    float* degf = (float*)(wp + 65536);          // N f32
    int* offs   = (int*)(degf + N);              // N+1
    const int nwg = (E + CH - 1) / CH;           // 391
    const int NB  = (N + 255) >> BSH;            // 391
    int* hist   = offs + (N + 1);                // NB*nwg
    int* bsum   = hist + NB * nwg;               // 256
    unsigned* packed = (unsigned*)(bsum + 256);  // E
    int* perm   = (int*)(packed + E);            // E

    const int nb = (N + 63) / 64;
    const int gb = (N + 3) / 4;
    const int nh = NB * nwg;
    const int nsb = (nh + 1023) / 1024;          // 150 < 256

    // ---- CSR build: two-level multisplit (no global atomics) ----
    bin_hist<<<nwg, 256, 0, stream>>>(ei, hist, E, nwg, NB);
    greduce<<<nsb, 256, 0, stream>>>(hist, bsum, nh);
    scan_bsums<<<1, 256, 0, stream>>>(bsum, nsb);
    gapply<<<nsb, 256, 0, stream>>>(hist, bsum, nh);
    bin_scatter<<<nwg, 256, 0, stream>>>(ei, hist, packed, E, nwg, NB);
    bucket_sort<<<NB, 256, 0, stream>>>(packed, hist, offs, degf, perm, E, nwg, NB, N);

    pack_weights<<<256, 256, 0, stream>>>(lin_W, c1_Wl, c1_Wr, c2_Wl, c2_Wr, wp);

    // layer 1: h1 = relu(x @ lin_W^T + lin_b)   (f32 staged directly)
    gemm_lin<<<nb, 256, 0, stream>>>(x, wp, lin_b, h1, N);

    // conv1 aggregation
    gather_mean_128<<<gb, 256, 0, stream>>>(h1, offs, perm, degf, aggb, N);

    // conv1 GEMM + conv2 dual GEMM fused (h2 stays in LDS)
    gemm_c1c2<<<nb, 256, 0, stream>>>(
        aggb, h1, wp + 16384, wp + 32768, wp + 49152, wp + 57344,
        c1_bl, c2_bl, g2, r2, N);

    // conv2 tail: out = log_softmax(gather_mean(g2) + r2)
    gather_out<<<gb, 256, 0, stream>>>(g2, r2, offs, perm, degf, out, N);
}